// Round 6
// baseline (687.199 us; speedup 1.0000x reference)
//
#include <hip/hip_runtime.h>

// GAT fused kernel for MI355X (gfx950) -- round 8.
// B=32768 graphs, N=14 nodes, F=C=128, E=64 edges (+14 self loops).
//
// Round-7 post-mortem: third spill at capped bounds. Root cause: lr=0
// materialized oacc[8] (32 acc) across the whole P@h epilogue because the
// xg/ht LDS union forces all-tiles-before-first-write. Fixes this round:
//  1. In-place per-tile P@h (lr=0): read ht_t -> MFMA -> relu -> f2bf ->
//     write x2 into the SAME region. WAR-safe: write data depends on MFMA,
//     which lgkmcnt-waits on the read; tile regions disjoint. oacc gone
//     (per-tile oc[4]); acc peak = hacc(16)+oc(4) = 20.
//  2. xg region deleted; layer-2 A-frags re-fragmented from x2-in-ht-layout
//     via 32 ds_read_u16 (once per kernel). Node de-swizzle: node l of col
//     c=ks*32+q*8+j sits at c*16 + (l ^ ((j>>2)<<3))  [position(n)=n^swx].
//  3. LDS 5312 B/wave (21248/block); 2 epilogue fences removed.
//  4. True peak ~86 regs -> __launch_bounds__(256,5) now has headroom
//     (budget ~96-102); 5 waves/SIMD, LDS allows 7 blocks -> 20 waves/CU.
// Kept: split h-GEMM (hacc[4] x 2 halves), lgkmcnt-only fences, ht XOR
// swizzle (BANK_CONFLICT 7.6M->3.4M), lr=1 P@h folded into pred dot,
// alpha scatter after one-time vmcnt(0).

#define NEG_SLOPE 0.2f

typedef __bf16 bf16x8 __attribute__((ext_vector_type(8)));
typedef float f32x4 __attribute__((ext_vector_type(4)));
typedef unsigned short us4v __attribute__((ext_vector_type(4)));
typedef unsigned short us8v __attribute__((ext_vector_type(8)));

static __device__ __forceinline__ unsigned short f2bf(float f) {
  unsigned u = __builtin_bit_cast(unsigned, f);
  return (unsigned short)((u + 0x7FFFu + ((u >> 16) & 1u)) >> 16); // RNE, finite
}

// Wave-internal LDS ordering: all communication is wave-private LDS, so a
// plain lgkmcnt(0) suffices; sched_barrier keeps the compiler from hoisting
// dependent ops past the inline-asm wait (guide rule #18).
static __device__ __forceinline__ void lds_fence() {
  asm volatile("s_waitcnt lgkmcnt(0)" ::: "memory");
  __builtin_amdgcn_sched_barrier(0);
}

// ---------------- setup: W frags (bf16, wave-load order) + weffc ----------------
// wfrag short offset: (((lr*4+ks)*8+t)*64 + lane)*8 ; element j = W[ks*32+q*8+j][t*16+l]
// weffc[(t*64+lane)*4+r] = (4q+r)<14 ? sum_c Wl[((4q+r)*128+t*16+l)*64+c]*Wp[c] : 0
__global__ void gat_setup_kernel(const float* __restrict__ W1, const float* __restrict__ W2,
                                 const float* __restrict__ Wl, const float* __restrict__ bl,
                                 const float* __restrict__ Wp, const float* __restrict__ bp,
                                 unsigned short* __restrict__ wfrag, float* __restrict__ weffc) {
  const int blk = blockIdx.x, tid = threadIdx.x; // 17 blocks x 256
  if (blk < 16) {
    int slot = blk * 256 + tid; // (lr,ks,t,lane)
    int lane = slot & 63, t = (slot >> 6) & 7, ks = (slot >> 9) & 3, lr = slot >> 11;
    const float* W = lr ? W2 : W1;
    int q = lane >> 4, l = lane & 15;
    int n = t * 16 + l, k0 = ks * 32 + q * 8;
    us8v hv;
    #pragma unroll
    for (int j = 0; j < 8; ++j) hv[j] = f2bf(W[(k0 + j) * 128 + n]);
    *(us8v*)(wfrag + slot * 8) = hv;
  } else {
    for (int i = tid; i < 2048; i += 256) {
      int r = i & 3, lane = (i >> 2) & 63, t = i >> 8;
      int q = lane >> 4, l = lane & 15;
      int row = 4 * q + r, col = t * 16 + l;
      float s = 0.f;
      if (row < 14) {
        const float* wl = Wl + (size_t)(row * 128 + col) * 64;
        #pragma unroll 8
        for (int c = 0; c < 64; ++c) s += wl[c] * Wp[c];
      }
      weffc[i] = s;
    }
    if (tid == 0) {
      float s = 0.f;
      for (int c = 0; c < 64; ++c) s += bl[c] * Wp[c];
      weffc[2048] = s + bp[0];
    }
  }
}

// Wave-private LDS scratch, 5312 B.
struct __align__(16) WaveLds {
  unsigned short xh[2048]; // ht[128][16] swz: h^T (P@h B-op) / x2^T between layers
  float Pf[256];           // unnormalized P f32 [16][16] [dst][src] (ds_add_f32)
  float asn[16], adn[16], mz[16];
};

__global__ __launch_bounds__(256, 5) void gat_kernel(
    const float* __restrict__ feat, const int* __restrict__ edges,
    const float* __restrict__ as1v, const float* __restrict__ ad1v,
    const float* __restrict__ b1v, const float* __restrict__ as2v,
    const float* __restrict__ ad2v, const float* __restrict__ b2v,
    const unsigned short* __restrict__ wfrag, const float* __restrict__ weffc,
    float* __restrict__ out) {
  __shared__ WaveLds wls[4];
  const int tid = threadIdx.x;
  const int wave = tid >> 6, lane = tid & 63;
  const int q = lane >> 4, l = lane & 15;
  const int swx = ((l >> 2) & 1) << 3; // ht bank swizzle (shorts); flips bit 3
  const int g = blockIdx.x * 4 + wave;
  WaveLds& S = wls[wave];

  // zero this graph's attn slice early; scatter overwrites after vmcnt(0)
  float* oa = out + 32768 + (size_t)g * 196; // 196 = 49 * f32x4, 16B-aligned
  if (lane < 49) *(f32x4*)(oa + lane * 4) = (f32x4){0.f, 0.f, 0.f, 0.f};

  // edge endpoints, one edge per lane (E=64)
  int esrc, edst;
  { const int2 e2 = *(const int2*)(edges + (size_t)g * 128 + lane * 2); esrc = e2.x; edst = e2.y; }

  us8v z8v = {0, 0, 0, 0, 0, 0, 0, 0};
  const bf16x8 zf = __builtin_bit_cast(bf16x8, z8v);

  // A-fragments of the current layer's h-GEMM. Layer 1: straight from global
  // feature (rows l>=14 zero). Layer 2: re-fragmented from x2 (ht layout).
  bf16x8 afr[4];
  if (l < 14) {
    const float* fb = feat + (size_t)g * 1792 + l * 128 + q * 8;
    #pragma unroll
    for (int ks = 0; ks < 4; ++ks) {
      f32x4 v0 = *(const f32x4*)(fb + ks * 32);
      f32x4 v1 = *(const f32x4*)(fb + ks * 32 + 4);
      us8v hv;
      hv[0] = f2bf(v0[0]); hv[1] = f2bf(v0[1]); hv[2] = f2bf(v0[2]); hv[3] = f2bf(v0[3]);
      hv[4] = f2bf(v1[0]); hv[5] = f2bf(v1[1]); hv[6] = f2bf(v1[2]); hv[7] = f2bf(v1[3]);
      afr[ks] = __builtin_bit_cast(bf16x8, hv);
    }
  } else {
    #pragma unroll
    for (int ks = 0; ks < 4; ++ks) afr[ks] = zf;
  }

  for (int lr = 0; lr < 2; ++lr) {
    const float* asv = lr ? as2v : as1v;
    const float* adv = lr ? ad2v : ad1v;
    const float* bsv = lr ? b2v : b1v;
    const unsigned short* wfl = wfrag + lr * 16384;

    // ---- h = x @ W in two t-halves (hacc[4] liveness, not hacc[8]) ----
    f32x4 pas = {0.f, 0.f, 0.f, 0.f}, padv = {0.f, 0.f, 0.f, 0.f};
    #pragma unroll
    for (int half = 0; half < 2; ++half) {
      f32x4 hacc[4];
      #pragma unroll
      for (int tt = 0; tt < 4; ++tt) hacc[tt] = (f32x4){0.f, 0.f, 0.f, 0.f};
      #pragma unroll
      for (int ks = 0; ks < 4; ++ks) {
        const unsigned short* wk = wfl + ks * 4096 + half * 2048 + lane * 8;
        #pragma unroll
        for (int tt = 0; tt < 4; ++tt) {
          bf16x8 bfv = *(const bf16x8*)(wk + tt * 512); // 16B/lane, coalesced, L2-hot
          hacc[tt] = __builtin_amdgcn_mfma_f32_16x16x32_bf16(afr[ks], bfv, hacc[tt], 0, 0, 0);
        }
      }
      // scores partial + ht store for this half's tiles, then hacc dies
      #pragma unroll
      for (int tt = 0; tt < 4; ++tt) {
        const int t = half * 4 + tt;
        float ca = asv[t * 16 + l], cd = adv[t * 16 + l]; // 512B arrays, L1-hot
        pas += hacc[tt] * ca;
        padv += hacc[tt] * cd;
        us4v hv;
        hv[0] = f2bf(hacc[tt][0]); hv[1] = f2bf(hacc[tt][1]);
        hv[2] = f2bf(hacc[tt][2]); hv[3] = f2bf(hacc[tt][3]);
        *(us4v*)(&S.xh[(t * 16 + l) * 16 + ((q * 4) ^ swx)]) = hv;
      }
    }

    // ---- node scores: butterfly over l (no LDS) ----
    #pragma unroll
    for (int m = 1; m <= 8; m <<= 1) {
      #pragma unroll
      for (int r = 0; r < 4; ++r) {
        pas[r] += __shfl_xor(pas[r], m, 64);
        padv[r] += __shfl_xor(padv[r], m, 64);
      }
    }
    if (l == 0) {
      #pragma unroll
      for (int r = 0; r < 4; ++r) { S.asn[4 * q + r] = pas[r]; S.adn[4 * q + r] = padv[r]; }
    }
    *(f32x4*)(&S.Pf[lane * 4]) = (f32x4){0.f, 0.f, 0.f, 0.f};
    lds_fence();

    // ---- edges: ev = exp(leaky(asn[src]+adn[dst])); accumulate unnormalized P ----
    float ev, ev2 = 0.f;
    {
      float f = S.asn[esrc] + S.adn[edst];
      ev = __expf(f > 0.f ? f : NEG_SLOPE * f);
      atomicAdd(&S.Pf[edst * 16 + esrc], ev); // duplicates accumulate (matches ref msg-sum)
      if (lane < 14) { // self loops
        float f2 = S.asn[lane] + S.adn[lane];
        ev2 = __expf(f2 > 0.f ? f2 : NEG_SLOPE * f2);
        atomicAdd(&S.Pf[lane * 17], ev2);
      }
    }
    lds_fence();

    // ---- per-dst 1/z = 1/rowsum(Pf) (16 lanes, 4x f32x4 each) ----
    if (lane < 16) {
      f32x4 s0 = *(const f32x4*)(&S.Pf[lane * 16]) + *(const f32x4*)(&S.Pf[lane * 16 + 4]) +
                 *(const f32x4*)(&S.Pf[lane * 16 + 8]) + *(const f32x4*)(&S.Pf[lane * 16 + 12]);
      float z = s0[0] + s0[1] + s0[2] + s0[3];
      S.mz[lane] = (lane < 14) ? 1.f / z : 0.f;
    }
    lds_fence();

    // ---- P@h A-frag straight from Pf (cols 14/15 of Pf are zero by construction) ----
    bf16x8 paf = zf;
    if (q < 2 && l < 14) {
      float m = S.mz[l];
      f32x4 p0 = *(const f32x4*)(&S.Pf[l * 16 + q * 8]);
      f32x4 p1 = *(const f32x4*)(&S.Pf[l * 16 + q * 8 + 4]);
      us8v hv;
      hv[0] = f2bf(p0[0] * m); hv[1] = f2bf(p0[1] * m);
      hv[2] = f2bf(p0[2] * m); hv[3] = f2bf(p0[3] * m);
      hv[4] = f2bf(p1[0] * m); hv[5] = f2bf(p1[1] * m);
      hv[6] = f2bf(p1[2] * m); hv[7] = f2bf(p1[3] * m);
      paf = __builtin_bit_cast(bf16x8, hv);
    }

    if (lr == 0) {
      // ---- out1 tile-by-tile, in place: read ht_t, MFMA, relu, write x2
      //      back into ht_t. Write data depends on the MFMA, which waits on
      //      the read via lgkmcnt -> no WAR hazard; tile regions disjoint.
      //      Rows 14/15 get relu(b1) garbage -- multiplied by zero P cols
      //      in layer 2, harmless (same as previous rounds). ----
      #pragma unroll
      for (int t = 0; t < 8; ++t) {
        float bb = bsv[t * 16 + l];
        f32x4 oc = (f32x4){bb, bb, bb, bb};
        bf16x8 hbf = (q < 2) ? *(const bf16x8*)(&S.xh[(t * 16 + l) * 16 + ((q * 8) ^ swx)]) : zf;
        oc = __builtin_amdgcn_mfma_f32_16x16x32_bf16(paf, hbf, oc, 0, 0, 0);
        us4v hv;
        hv[0] = f2bf(fmaxf(oc[0], 0.f)); hv[1] = f2bf(fmaxf(oc[1], 0.f));
        hv[2] = f2bf(fmaxf(oc[2], 0.f)); hv[3] = f2bf(fmaxf(oc[3], 0.f));
        *(us4v*)(&S.xh[(t * 16 + l) * 16 + ((q * 4) ^ swx)]) = hv;
      }
      lds_fence();
      // re-fragment layer-2 A-op from x2 in ht layout: node l of col c is at
      // c*16 + (l ^ ((j>>2)<<3))   [stored position(n) = n ^ swx(col)]
      #pragma unroll
      for (int ks = 0; ks < 4; ++ks) {
        us8v hv;
        #pragma unroll
        for (int j = 0; j < 8; ++j)
          hv[j] = S.xh[(ks * 32 + q * 8 + j) * 16 + (l ^ ((j >> 2) << 3))];
        afr[ks] = __builtin_bit_cast(bf16x8, hv);
      }
    } else {
      // ---- layer-2 alpha straight to global (zeros from entry drained first) ----
      asm volatile("s_waitcnt vmcnt(0)" ::: "memory"); // order scatter after zero-stores
      oa[esrc * 14 + edst] = ev * S.mz[edst]; // duplicates write identical bits
      if (lane < 14) oa[lane * 15] = ev2 * S.mz[lane];

      // ---- out2 = P@h + b, folded per-tile into pred dot (oc dead immediately) ----
      float part = 0.f;
      #pragma unroll
      for (int t = 0; t < 8; ++t) {
        float bb = bsv[t * 16 + l];
        f32x4 oc = (f32x4){bb, bb, bb, bb};
        bf16x8 hbf = (q < 2) ? *(const bf16x8*)(&S.xh[(t * 16 + l) * 16 + ((q * 8) ^ swx)]) : zf;
        oc = __builtin_amdgcn_mfma_f32_16x16x32_bf16(paf, hbf, oc, 0, 0, 0);
        f32x4 wv = *(const f32x4*)(weffc + t * 256 + lane * 4); // coalesced, L2-hot
        part += oc[0] * wv[0] + oc[1] * wv[1] + oc[2] * wv[2] + oc[3] * wv[3];
      }
      #pragma unroll
      for (int m = 1; m < 64; m <<= 1) part += __shfl_xor(part, m, 64);
      if (lane == 0) {
        float p = 1.f / (1.f + __expf(-(part + weffc[2048])));
        out[g] = p;
      }
    }
  }
}

extern "C" void kernel_launch(void* const* d_in, const int* in_sizes, int n_in,
                              void* d_out, int out_size, void* d_ws, size_t ws_size,
                              hipStream_t stream) {
  const float* feat = (const float*)d_in[0];
  const int* edges = (const int*)d_in[1];
  const float* W1 = (const float*)d_in[2];
  const float* as1 = (const float*)d_in[3];
  const float* ad1 = (const float*)d_in[4];
  const float* b1 = (const float*)d_in[5];
  const float* W2 = (const float*)d_in[6];
  const float* as2 = (const float*)d_in[7];
  const float* ad2 = (const float*)d_in[8];
  const float* b2 = (const float*)d_in[9];
  const float* Wl = (const float*)d_in[10];
  const float* bl = (const float*)d_in[11];
  const float* Wp = (const float*)d_in[12];
  const float* bp = (const float*)d_in[13];

  unsigned short* wfrag = (unsigned short*)d_ws;          // 65536 B
  float* weffc = (float*)((char*)d_ws + 65536);           // 2049 f32

  gat_setup_kernel<<<17, 256, 0, stream>>>(W1, W2, Wl, bl, Wp, bp, wfrag, weffc);
  gat_kernel<<<8192, 256, 0, stream>>>(feat, edges, as1, ad1, b1, as2, ad2, b2,
                                       wfrag, weffc, (float*)d_out);
}

// Round 7
// 541.811 us; speedup vs baseline: 1.2683x; 1.2683x over previous
//
#include <hip/hip_runtime.h>

// GAT fused kernel for MI355X (gfx950) -- round 9.
// B=32768 graphs, N=14 nodes, F=C=128, E=64 edges (+14 self loops).
//
// Round-8 post-mortem: 4th consecutive spill at raised launch bounds.
// Even with oacc[8] eliminated (acc peak ~20), budget<=102 spills: the
// residual pressure is the fully-unrolled B-frag prefetch (scheduler
// holds many 16B loads in flight and prefers spilling accs over
// serializing loads). VGPR_Count (48) excludes the acc half of the
// unified file -- true allocation ~budget.
// This round: clean A/B of the round-8 structure -- ONLY change is
// __launch_bounds__(256,4) (budget 128, proven no-spill). Note the 2nd
// arg is a MINIMUM: if natural allocation lands <=102 total, HW runs 5
// blocks/CU anyway. Expected: WRITE ~47MB / FETCH ~125MB (spill gone);
// dur ~170-195us if Occ ~53%, ~195-215us if Occ stays 43%.
// Kept from round 8: in-place per-tile P@h (lr=0) with x2 written back
// into ht region (WAR-safe via MFMA's lgkmcnt dependence); xg deleted;
// layer-2 A-frags re-fragmented from x2-in-ht-layout (32 ds_read_u16,
// once per kernel); LDS 5312B/wave; split h-GEMM (hacc[4] x 2 halves);
// lgkmcnt-only fences; ht XOR swizzle; lr=1 P@h folded into pred dot;
// alpha scatter after one-time vmcnt(0).

#define NEG_SLOPE 0.2f

typedef __bf16 bf16x8 __attribute__((ext_vector_type(8)));
typedef float f32x4 __attribute__((ext_vector_type(4)));
typedef unsigned short us4v __attribute__((ext_vector_type(4)));
typedef unsigned short us8v __attribute__((ext_vector_type(8)));

static __device__ __forceinline__ unsigned short f2bf(float f) {
  unsigned u = __builtin_bit_cast(unsigned, f);
  return (unsigned short)((u + 0x7FFFu + ((u >> 16) & 1u)) >> 16); // RNE, finite
}

// Wave-internal LDS ordering: all communication is wave-private LDS, so a
// plain lgkmcnt(0) suffices; sched_barrier keeps the compiler from hoisting
// dependent ops past the inline-asm wait (guide rule #18).
static __device__ __forceinline__ void lds_fence() {
  asm volatile("s_waitcnt lgkmcnt(0)" ::: "memory");
  __builtin_amdgcn_sched_barrier(0);
}

// ---------------- setup: W frags (bf16, wave-load order) + weffc ----------------
// wfrag short offset: (((lr*4+ks)*8+t)*64 + lane)*8 ; element j = W[ks*32+q*8+j][t*16+l]
// weffc[(t*64+lane)*4+r] = (4q+r)<14 ? sum_c Wl[((4q+r)*128+t*16+l)*64+c]*Wp[c] : 0
__global__ void gat_setup_kernel(const float* __restrict__ W1, const float* __restrict__ W2,
                                 const float* __restrict__ Wl, const float* __restrict__ bl,
                                 const float* __restrict__ Wp, const float* __restrict__ bp,
                                 unsigned short* __restrict__ wfrag, float* __restrict__ weffc) {
  const int blk = blockIdx.x, tid = threadIdx.x; // 17 blocks x 256
  if (blk < 16) {
    int slot = blk * 256 + tid; // (lr,ks,t,lane)
    int lane = slot & 63, t = (slot >> 6) & 7, ks = (slot >> 9) & 3, lr = slot >> 11;
    const float* W = lr ? W2 : W1;
    int q = lane >> 4, l = lane & 15;
    int n = t * 16 + l, k0 = ks * 32 + q * 8;
    us8v hv;
    #pragma unroll
    for (int j = 0; j < 8; ++j) hv[j] = f2bf(W[(k0 + j) * 128 + n]);
    *(us8v*)(wfrag + slot * 8) = hv;
  } else {
    for (int i = tid; i < 2048; i += 256) {
      int r = i & 3, lane = (i >> 2) & 63, t = i >> 8;
      int q = lane >> 4, l = lane & 15;
      int row = 4 * q + r, col = t * 16 + l;
      float s = 0.f;
      if (row < 14) {
        const float* wl = Wl + (size_t)(row * 128 + col) * 64;
        #pragma unroll 8
        for (int c = 0; c < 64; ++c) s += wl[c] * Wp[c];
      }
      weffc[i] = s;
    }
    if (tid == 0) {
      float s = 0.f;
      for (int c = 0; c < 64; ++c) s += bl[c] * Wp[c];
      weffc[2048] = s + bp[0];
    }
  }
}

// Wave-private LDS scratch, 5312 B.
struct __align__(16) WaveLds {
  unsigned short xh[2048]; // ht[128][16] swz: h^T (P@h B-op) / x2^T between layers
  float Pf[256];           // unnormalized P f32 [16][16] [dst][src] (ds_add_f32)
  float asn[16], adn[16], mz[16];
};

__global__ __launch_bounds__(256, 4) void gat_kernel(
    const float* __restrict__ feat, const int* __restrict__ edges,
    const float* __restrict__ as1v, const float* __restrict__ ad1v,
    const float* __restrict__ b1v, const float* __restrict__ as2v,
    const float* __restrict__ ad2v, const float* __restrict__ b2v,
    const unsigned short* __restrict__ wfrag, const float* __restrict__ weffc,
    float* __restrict__ out) {
  __shared__ WaveLds wls[4];
  const int tid = threadIdx.x;
  const int wave = tid >> 6, lane = tid & 63;
  const int q = lane >> 4, l = lane & 15;
  const int swx = ((l >> 2) & 1) << 3; // ht bank swizzle (shorts); flips bit 3
  const int g = blockIdx.x * 4 + wave;
  WaveLds& S = wls[wave];

  // zero this graph's attn slice early; scatter overwrites after vmcnt(0)
  float* oa = out + 32768 + (size_t)g * 196; // 196 = 49 * f32x4, 16B-aligned
  if (lane < 49) *(f32x4*)(oa + lane * 4) = (f32x4){0.f, 0.f, 0.f, 0.f};

  // edge endpoints, one edge per lane (E=64)
  int esrc, edst;
  { const int2 e2 = *(const int2*)(edges + (size_t)g * 128 + lane * 2); esrc = e2.x; edst = e2.y; }

  us8v z8v = {0, 0, 0, 0, 0, 0, 0, 0};
  const bf16x8 zf = __builtin_bit_cast(bf16x8, z8v);

  // A-fragments of the current layer's h-GEMM. Layer 1: straight from global
  // feature (rows l>=14 zero). Layer 2: re-fragmented from x2 (ht layout).
  bf16x8 afr[4];
  if (l < 14) {
    const float* fb = feat + (size_t)g * 1792 + l * 128 + q * 8;
    #pragma unroll
    for (int ks = 0; ks < 4; ++ks) {
      f32x4 v0 = *(const f32x4*)(fb + ks * 32);
      f32x4 v1 = *(const f32x4*)(fb + ks * 32 + 4);
      us8v hv;
      hv[0] = f2bf(v0[0]); hv[1] = f2bf(v0[1]); hv[2] = f2bf(v0[2]); hv[3] = f2bf(v0[3]);
      hv[4] = f2bf(v1[0]); hv[5] = f2bf(v1[1]); hv[6] = f2bf(v1[2]); hv[7] = f2bf(v1[3]);
      afr[ks] = __builtin_bit_cast(bf16x8, hv);
    }
  } else {
    #pragma unroll
    for (int ks = 0; ks < 4; ++ks) afr[ks] = zf;
  }

  for (int lr = 0; lr < 2; ++lr) {
    const float* asv = lr ? as2v : as1v;
    const float* adv = lr ? ad2v : ad1v;
    const float* bsv = lr ? b2v : b1v;
    const unsigned short* wfl = wfrag + lr * 16384;

    // ---- h = x @ W in two t-halves (hacc[4] liveness, not hacc[8]) ----
    f32x4 pas = {0.f, 0.f, 0.f, 0.f}, padv = {0.f, 0.f, 0.f, 0.f};
    #pragma unroll
    for (int half = 0; half < 2; ++half) {
      f32x4 hacc[4];
      #pragma unroll
      for (int tt = 0; tt < 4; ++tt) hacc[tt] = (f32x4){0.f, 0.f, 0.f, 0.f};
      #pragma unroll
      for (int ks = 0; ks < 4; ++ks) {
        const unsigned short* wk = wfl + ks * 4096 + half * 2048 + lane * 8;
        #pragma unroll
        for (int tt = 0; tt < 4; ++tt) {
          bf16x8 bfv = *(const bf16x8*)(wk + tt * 512); // 16B/lane, coalesced, L2-hot
          hacc[tt] = __builtin_amdgcn_mfma_f32_16x16x32_bf16(afr[ks], bfv, hacc[tt], 0, 0, 0);
        }
      }
      // scores partial + ht store for this half's tiles, then hacc dies
      #pragma unroll
      for (int tt = 0; tt < 4; ++tt) {
        const int t = half * 4 + tt;
        float ca = asv[t * 16 + l], cd = adv[t * 16 + l]; // 512B arrays, L1-hot
        pas += hacc[tt] * ca;
        padv += hacc[tt] * cd;
        us4v hv;
        hv[0] = f2bf(hacc[tt][0]); hv[1] = f2bf(hacc[tt][1]);
        hv[2] = f2bf(hacc[tt][2]); hv[3] = f2bf(hacc[tt][3]);
        *(us4v*)(&S.xh[(t * 16 + l) * 16 + ((q * 4) ^ swx)]) = hv;
      }
    }

    // ---- node scores: butterfly over l (no LDS) ----
    #pragma unroll
    for (int m = 1; m <= 8; m <<= 1) {
      #pragma unroll
      for (int r = 0; r < 4; ++r) {
        pas[r] += __shfl_xor(pas[r], m, 64);
        padv[r] += __shfl_xor(padv[r], m, 64);
      }
    }
    if (l == 0) {
      #pragma unroll
      for (int r = 0; r < 4; ++r) { S.asn[4 * q + r] = pas[r]; S.adn[4 * q + r] = padv[r]; }
    }
    *(f32x4*)(&S.Pf[lane * 4]) = (f32x4){0.f, 0.f, 0.f, 0.f};
    lds_fence();

    // ---- edges: ev = exp(leaky(asn[src]+adn[dst])); accumulate unnormalized P ----
    float ev, ev2 = 0.f;
    {
      float f = S.asn[esrc] + S.adn[edst];
      ev = __expf(f > 0.f ? f : NEG_SLOPE * f);
      atomicAdd(&S.Pf[edst * 16 + esrc], ev); // duplicates accumulate (matches ref msg-sum)
      if (lane < 14) { // self loops
        float f2 = S.asn[lane] + S.adn[lane];
        ev2 = __expf(f2 > 0.f ? f2 : NEG_SLOPE * f2);
        atomicAdd(&S.Pf[lane * 17], ev2);
      }
    }
    lds_fence();

    // ---- per-dst 1/z = 1/rowsum(Pf) (16 lanes, 4x f32x4 each) ----
    if (lane < 16) {
      f32x4 s0 = *(const f32x4*)(&S.Pf[lane * 16]) + *(const f32x4*)(&S.Pf[lane * 16 + 4]) +
                 *(const f32x4*)(&S.Pf[lane * 16 + 8]) + *(const f32x4*)(&S.Pf[lane * 16 + 12]);
      float z = s0[0] + s0[1] + s0[2] + s0[3];
      S.mz[lane] = (lane < 14) ? 1.f / z : 0.f;
    }
    lds_fence();

    // ---- P@h A-frag straight from Pf (cols 14/15 of Pf are zero by construction) ----
    bf16x8 paf = zf;
    if (q < 2 && l < 14) {
      float m = S.mz[l];
      f32x4 p0 = *(const f32x4*)(&S.Pf[l * 16 + q * 8]);
      f32x4 p1 = *(const f32x4*)(&S.Pf[l * 16 + q * 8 + 4]);
      us8v hv;
      hv[0] = f2bf(p0[0] * m); hv[1] = f2bf(p0[1] * m);
      hv[2] = f2bf(p0[2] * m); hv[3] = f2bf(p0[3] * m);
      hv[4] = f2bf(p1[0] * m); hv[5] = f2bf(p1[1] * m);
      hv[6] = f2bf(p1[2] * m); hv[7] = f2bf(p1[3] * m);
      paf = __builtin_bit_cast(bf16x8, hv);
    }

    if (lr == 0) {
      // ---- out1 tile-by-tile, in place: read ht_t, MFMA, relu, write x2
      //      back into ht_t. Write data depends on the MFMA, which waits on
      //      the read via lgkmcnt -> no WAR hazard; tile regions disjoint.
      //      Rows 14/15 get relu(b1) garbage -- multiplied by zero P cols
      //      in layer 2, harmless (same as previous rounds). ----
      #pragma unroll
      for (int t = 0; t < 8; ++t) {
        float bb = bsv[t * 16 + l];
        f32x4 oc = (f32x4){bb, bb, bb, bb};
        bf16x8 hbf = (q < 2) ? *(const bf16x8*)(&S.xh[(t * 16 + l) * 16 + ((q * 8) ^ swx)]) : zf;
        oc = __builtin_amdgcn_mfma_f32_16x16x32_bf16(paf, hbf, oc, 0, 0, 0);
        us4v hv;
        hv[0] = f2bf(fmaxf(oc[0], 0.f)); hv[1] = f2bf(fmaxf(oc[1], 0.f));
        hv[2] = f2bf(fmaxf(oc[2], 0.f)); hv[3] = f2bf(fmaxf(oc[3], 0.f));
        *(us4v*)(&S.xh[(t * 16 + l) * 16 + ((q * 4) ^ swx)]) = hv;
      }
      lds_fence();
      // re-fragment layer-2 A-op from x2 in ht layout: node l of col c is at
      // c*16 + (l ^ ((j>>2)<<3))   [stored position(n) = n ^ swx(col)]
      #pragma unroll
      for (int ks = 0; ks < 4; ++ks) {
        us8v hv;
        #pragma unroll
        for (int j = 0; j < 8; ++j)
          hv[j] = S.xh[(ks * 32 + q * 8 + j) * 16 + (l ^ ((j >> 2) << 3))];
        afr[ks] = __builtin_bit_cast(bf16x8, hv);
      }
    } else {
      // ---- layer-2 alpha straight to global (zeros from entry drained first) ----
      asm volatile("s_waitcnt vmcnt(0)" ::: "memory"); // order scatter after zero-stores
      oa[esrc * 14 + edst] = ev * S.mz[edst]; // duplicates write identical bits
      if (lane < 14) oa[lane * 15] = ev2 * S.mz[lane];

      // ---- out2 = P@h + b, folded per-tile into pred dot (oc dead immediately) ----
      float part = 0.f;
      #pragma unroll
      for (int t = 0; t < 8; ++t) {
        float bb = bsv[t * 16 + l];
        f32x4 oc = (f32x4){bb, bb, bb, bb};
        bf16x8 hbf = (q < 2) ? *(const bf16x8*)(&S.xh[(t * 16 + l) * 16 + ((q * 8) ^ swx)]) : zf;
        oc = __builtin_amdgcn_mfma_f32_16x16x32_bf16(paf, hbf, oc, 0, 0, 0);
        f32x4 wv = *(const f32x4*)(weffc + t * 256 + lane * 4); // coalesced, L2-hot
        part += oc[0] * wv[0] + oc[1] * wv[1] + oc[2] * wv[2] + oc[3] * wv[3];
      }
      #pragma unroll
      for (int m = 1; m < 64; m <<= 1) part += __shfl_xor(part, m, 64);
      if (lane == 0) {
        float p = 1.f / (1.f + __expf(-(part + weffc[2048])));
        out[g] = p;
      }
    }
  }
}

extern "C" void kernel_launch(void* const* d_in, const int* in_sizes, int n_in,
                              void* d_out, int out_size, void* d_ws, size_t ws_size,
                              hipStream_t stream) {
  const float* feat = (const float*)d_in[0];
  const int* edges = (const int*)d_in[1];
  const float* W1 = (const float*)d_in[2];
  const float* as1 = (const float*)d_in[3];
  const float* ad1 = (const float*)d_in[4];
  const float* b1 = (const float*)d_in[5];
  const float* W2 = (const float*)d_in[6];
  const float* as2 = (const float*)d_in[7];
  const float* ad2 = (const float*)d_in[8];
  const float* b2 = (const float*)d_in[9];
  const float* Wl = (const float*)d_in[10];
  const float* bl = (const float*)d_in[11];
  const float* Wp = (const float*)d_in[12];
  const float* bp = (const float*)d_in[13];

  unsigned short* wfrag = (unsigned short*)d_ws;          // 65536 B
  float* weffc = (float*)((char*)d_ws + 65536);           // 2049 f32

  gat_setup_kernel<<<17, 256, 0, stream>>>(W1, W2, Wl, bl, Wp, bp, wfrag, weffc);
  gat_kernel<<<8192, 256, 0, stream>>>(feat, edges, as1, ad1, b1, as2, ad2, b2,
                                       wfrag, weffc, (float*)d_out);
}

// Round 8
// 460.809 us; speedup vs baseline: 1.4913x; 1.1758x over previous
//
#include <hip/hip_runtime.h>

// GAT fused kernel for MI355X (gfx950) -- round 10.
// B=32768 graphs, N=14 nodes, F=C=128, E=64 edges (+14 self loops).
//
// Round-9 post-mortem: occupancy is STRUCTURALLY PINNED at ~45%: the
// allocator consumes the full 128-reg/wave budget at (256,4) (arch+acc+
// prefetch), giving 4 waves/SIMD; every <=102 budget spilled (4/4 tries).
// Round-8 structure also regressed (266us vs round-5's 218us, WRITE 155MB
// residual scratch). This round consolidates on the PROVEN round-5
// structure (218us, VGPR 56, WRITE 47MB) + four local cuts to the
// per-wave latency chain (~65k cy/wave, issue only ~4k):
//  1. Native bf16 casts ((__bf16)f -> v_cvt_pk_bf16_f32) replacing the
//     4-op integer-RNE trick (~140 sites, ~550 VALU/wave saved). RNE
//     either way -> bit-identical output.
//  2. ht XOR swizzle ^((l>>2)&1)<<3 (validated r6-r9; conflicts 7.6M->3.4M).
//  3. s_setprio(1/0) around MFMA clusters (T5 regime: independent waves
//     at different phases -- ours).
//  4. 64-lane Pf rowsum (1 f32x4 read + 2 shfl vs 16 lanes x 4 reads).
// Kept from r5: hacc[8] single-pass h-GEMM, oacc[8] epilogue, xg[16][136]
// union, LDS 5568B/wave, lgkmcnt-only fences, alpha scatter, (256,4).

#define NEG_SLOPE 0.2f

typedef __bf16 bf16x8 __attribute__((ext_vector_type(8)));
typedef float f32x4 __attribute__((ext_vector_type(4)));
typedef unsigned short us4v __attribute__((ext_vector_type(4)));
typedef unsigned short us8v __attribute__((ext_vector_type(8)));

static __device__ __forceinline__ unsigned short f2bf(float f) {
  __bf16 h = (__bf16)f; // compiler emits v_cvt_pk_bf16_f32 (RNE), pairs fuse
  return __builtin_bit_cast(unsigned short, h);
}

// Wave-internal LDS ordering: all communication is wave-private LDS, so a
// plain lgkmcnt(0) suffices; sched_barrier keeps the compiler from hoisting
// dependent ops past the inline-asm wait (guide rule #18).
static __device__ __forceinline__ void lds_fence() {
  asm volatile("s_waitcnt lgkmcnt(0)" ::: "memory");
  __builtin_amdgcn_sched_barrier(0);
}

// ---------------- setup: W frags (bf16, wave-load order) + weffc ----------------
// wfrag short offset: (((lr*4+ks)*8+t)*64 + lane)*8 ; element j = W[ks*32+q*8+j][t*16+l]
// weffc[(t*64+lane)*4+r] = (4q+r)<14 ? sum_c Wl[((4q+r)*128+t*16+l)*64+c]*Wp[c] : 0
__global__ void gat_setup_kernel(const float* __restrict__ W1, const float* __restrict__ W2,
                                 const float* __restrict__ Wl, const float* __restrict__ bl,
                                 const float* __restrict__ Wp, const float* __restrict__ bp,
                                 unsigned short* __restrict__ wfrag, float* __restrict__ weffc) {
  const int blk = blockIdx.x, tid = threadIdx.x; // 17 blocks x 256
  if (blk < 16) {
    int slot = blk * 256 + tid; // (lr,ks,t,lane)
    int lane = slot & 63, t = (slot >> 6) & 7, ks = (slot >> 9) & 3, lr = slot >> 11;
    const float* W = lr ? W2 : W1;
    int q = lane >> 4, l = lane & 15;
    int n = t * 16 + l, k0 = ks * 32 + q * 8;
    us8v hv;
    #pragma unroll
    for (int j = 0; j < 8; ++j) hv[j] = f2bf(W[(k0 + j) * 128 + n]);
    *(us8v*)(wfrag + slot * 8) = hv;
  } else {
    for (int i = tid; i < 2048; i += 256) {
      int r = i & 3, lane = (i >> 2) & 63, t = i >> 8;
      int q = lane >> 4, l = lane & 15;
      int row = 4 * q + r, col = t * 16 + l;
      float s = 0.f;
      if (row < 14) {
        const float* wl = Wl + (size_t)(row * 128 + col) * 64;
        #pragma unroll 8
        for (int c = 0; c < 64; ++c) s += wl[c] * Wp[c];
      }
      weffc[i] = s;
    }
    if (tid == 0) {
      float s = 0.f;
      for (int c = 0; c < 64; ++c) s += bl[c] * Wp[c];
      weffc[2048] = s + bp[0];
    }
  }
}

// Wave-private LDS scratch, 5568 B.
struct __align__(16) WaveLds {
  unsigned short xh[2176]; // xg[16][136] (layer-2 A-op) / ht[128][16] swz (P@h B-op)
  float Pf[256];           // unnormalized P f32 [16][16] [dst][src] (ds_add_f32)
  float asn[16], adn[16], mz[16];
};

__global__ __launch_bounds__(256, 4) void gat_kernel(
    const float* __restrict__ feat, const int* __restrict__ edges,
    const float* __restrict__ as1v, const float* __restrict__ ad1v,
    const float* __restrict__ b1v, const float* __restrict__ as2v,
    const float* __restrict__ ad2v, const float* __restrict__ b2v,
    const unsigned short* __restrict__ wfrag, const float* __restrict__ weffc,
    float* __restrict__ out) {
  __shared__ WaveLds wls[4];
  const int tid = threadIdx.x;
  const int wave = tid >> 6, lane = tid & 63;
  const int q = lane >> 4, l = lane & 15;
  const int swx = ((l >> 2) & 1) << 3; // ht bank swizzle (shorts); per-column XOR
  const int g = blockIdx.x * 4 + wave;
  WaveLds& S = wls[wave];

  // zero this graph's attn slice early; scatter overwrites after vmcnt(0)
  float* oa = out + 32768 + (size_t)g * 196; // 196 = 49 * f32x4, 16B-aligned
  if (lane < 49) *(f32x4*)(oa + lane * 4) = (f32x4){0.f, 0.f, 0.f, 0.f};

  // edge endpoints, one edge per lane (E=64)
  int esrc, edst;
  { const int2 e2 = *(const int2*)(edges + (size_t)g * 128 + lane * 2); esrc = e2.x; edst = e2.y; }

  us8v z8v = {0, 0, 0, 0, 0, 0, 0, 0};
  const bf16x8 zf = __builtin_bit_cast(bf16x8, z8v);

  // layer-1 A-fragments straight from global feature; rows m=l>=14 are zero
  bf16x8 af1[4];
  if (l < 14) {
    const float* fb = feat + (size_t)g * 1792 + l * 128 + q * 8;
    #pragma unroll
    for (int ks = 0; ks < 4; ++ks) {
      f32x4 v0 = *(const f32x4*)(fb + ks * 32);
      f32x4 v1 = *(const f32x4*)(fb + ks * 32 + 4);
      us8v hv;
      hv[0] = f2bf(v0[0]); hv[1] = f2bf(v0[1]); hv[2] = f2bf(v0[2]); hv[3] = f2bf(v0[3]);
      hv[4] = f2bf(v1[0]); hv[5] = f2bf(v1[1]); hv[6] = f2bf(v1[2]); hv[7] = f2bf(v1[3]);
      af1[ks] = __builtin_bit_cast(bf16x8, hv);
    }
  } else {
    #pragma unroll
    for (int ks = 0; ks < 4; ++ks) af1[ks] = zf;
  }

  f32x4 oacc[8];

  for (int lr = 0; lr < 2; ++lr) {
    const float* asv = lr ? as2v : as1v;
    const float* adv = lr ? ad2v : ad1v;
    const float* bsv = lr ? b2v : b1v;
    const unsigned short* wfl = wfrag + lr * 16384;

    // ---- h = x @ W (M=16, N=128 in 8 tiles, K=128 in 4 steps); B-frags from L2 ----
    f32x4 hacc[8];
    #pragma unroll
    for (int t = 0; t < 8; ++t) hacc[t] = (f32x4){0.f, 0.f, 0.f, 0.f};
    __builtin_amdgcn_s_setprio(1);
    #pragma unroll
    for (int ks = 0; ks < 4; ++ks) {
      bf16x8 af = lr ? *(const bf16x8*)(&S.xh[l * 136 + ks * 32 + q * 8]) : af1[ks];
      const unsigned short* wk = wfl + ks * 4096 + lane * 8;
      #pragma unroll
      for (int t = 0; t < 8; ++t) {
        bf16x8 bfv = *(const bf16x8*)(wk + t * 512); // 16B/lane, coalesced, L2-hot
        hacc[t] = __builtin_amdgcn_mfma_f32_16x16x32_bf16(af, bfv, hacc[t], 0, 0, 0);
      }
    }
    __builtin_amdgcn_s_setprio(0);

    // ---- node scores: per-lane partial over cols, butterfly over l (no LDS) ----
    f32x4 pas = {0.f, 0.f, 0.f, 0.f}, padv = {0.f, 0.f, 0.f, 0.f};
    #pragma unroll
    for (int t = 0; t < 8; ++t) {
      float ca = asv[t * 16 + l], cd = adv[t * 16 + l]; // 512B arrays, L1-hot
      pas += hacc[t] * ca;
      padv += hacc[t] * cd;
    }
    #pragma unroll
    for (int m = 1; m <= 8; m <<= 1) {
      #pragma unroll
      for (int r = 0; r < 4; ++r) {
        pas[r] += __shfl_xor(pas[r], m, 64);
        padv[r] += __shfl_xor(padv[r], m, 64);
      }
    }
    if (l == 0) {
      #pragma unroll
      for (int r = 0; r < 4; ++r) { S.asn[4 * q + r] = pas[r]; S.adn[4 * q + r] = padv[r]; }
    }

    // ---- h -> ht[128][16] bf16 (P@h B-op), column-chunk XOR swizzled ----
    #pragma unroll
    for (int t = 0; t < 8; ++t) {
      us4v hv;
      hv[0] = f2bf(hacc[t][0]); hv[1] = f2bf(hacc[t][1]);
      hv[2] = f2bf(hacc[t][2]); hv[3] = f2bf(hacc[t][3]);
      *(us4v*)(&S.xh[(t * 16 + l) * 16 + ((q * 4) ^ swx)]) = hv;
    }
    *(f32x4*)(&S.Pf[lane * 4]) = (f32x4){0.f, 0.f, 0.f, 0.f};
    lds_fence();

    // ---- edges: ev = exp(leaky(asn[src]+adn[dst])); accumulate unnormalized P ----
    float ev, ev2 = 0.f;
    {
      float f = S.asn[esrc] + S.adn[edst];
      ev = __expf(f > 0.f ? f : NEG_SLOPE * f);
      atomicAdd(&S.Pf[edst * 16 + esrc], ev); // duplicates accumulate (matches ref msg-sum)
      if (lane < 14) { // self loops
        float f2 = S.asn[lane] + S.adn[lane];
        ev2 = __expf(f2 > 0.f ? f2 : NEG_SLOPE * f2);
        atomicAdd(&S.Pf[lane * 17], ev2);
      }
    }
    lds_fence();

    // ---- per-dst 1/z = 1/rowsum(Pf), all 64 lanes (lane -> d=lane>>2, chunk) ----
    {
      int d = lane >> 2;
      f32x4 s0 = *(const f32x4*)(&S.Pf[d * 16 + (lane & 3) * 4]);
      float z = s0[0] + s0[1] + s0[2] + s0[3];
      z += __shfl_xor(z, 1, 64);
      z += __shfl_xor(z, 2, 64);
      if ((lane & 3) == 0) S.mz[d] = (d < 14) ? 1.f / z : 0.f;
    }
    lds_fence();

    // ---- P@h A-frag straight from Pf (cols 14/15 of Pf are zero by construction) ----
    bf16x8 paf = zf;
    if (q < 2 && l < 14) {
      float m = S.mz[l];
      f32x4 p0 = *(const f32x4*)(&S.Pf[l * 16 + q * 8]);
      f32x4 p1 = *(const f32x4*)(&S.Pf[l * 16 + q * 8 + 4]);
      us8v hv;
      hv[0] = f2bf(p0[0] * m); hv[1] = f2bf(p0[1] * m);
      hv[2] = f2bf(p0[2] * m); hv[3] = f2bf(p0[3] * m);
      hv[4] = f2bf(p1[0] * m); hv[5] = f2bf(p1[1] * m);
      hv[6] = f2bf(p1[2] * m); hv[7] = f2bf(p1[3] * m);
      paf = __builtin_bit_cast(bf16x8, hv);
    }

    // ---- layer-2 alpha straight to global (zeros from entry are drained first) ----
    if (lr) {
      asm volatile("s_waitcnt vmcnt(0)" ::: "memory"); // order scatter after zero-stores
      oa[esrc * 14 + edst] = ev * S.mz[edst]; // duplicates write identical bits
      if (lane < 14) oa[lane * 15] = ev2 * S.mz[lane];
    }

    // ---- out = P @ h + b (K=32; quads>=2 feed zero frags) ----
    #pragma unroll
    for (int t = 0; t < 8; ++t) {
      float bb = bsv[t * 16 + l];
      oacc[t] = (f32x4){bb, bb, bb, bb};
    }
    __builtin_amdgcn_s_setprio(1);
    #pragma unroll
    for (int t = 0; t < 8; ++t) {
      bf16x8 hbf = (q < 2) ? *(const bf16x8*)(&S.xh[(t * 16 + l) * 16 + ((q * 8) ^ swx)]) : zf;
      oacc[t] = __builtin_amdgcn_mfma_f32_16x16x32_bf16(paf, hbf, oacc[t], 0, 0, 0);
    }
    __builtin_amdgcn_s_setprio(0);

    if (lr == 0) {
      // x2 = relu(out1) -> xg[16][136] for layer-2 A-op
      lds_fence(); // ht reads complete before overwrite
      #pragma unroll
      for (int t = 0; t < 8; ++t) {
        #pragma unroll
        for (int r = 0; r < 4; ++r) {
          float v = fmaxf(oacc[t][r], 0.f);
          S.xh[(4 * q + r) * 136 + t * 16 + l] = f2bf(v);
        }
      }
      lds_fence();
    }
  }

  // ---- pred = sigmoid(sum oacc .* weffc + beff); weffc pre-masked rows>=14 ----
  float part = 0.f;
  #pragma unroll
  for (int t = 0; t < 8; ++t) {
    f32x4 wv = *(const f32x4*)(weffc + t * 256 + lane * 4); // coalesced, L2-hot
    part += oacc[t][0] * wv[0] + oacc[t][1] * wv[1] + oacc[t][2] * wv[2] + oacc[t][3] * wv[3];
  }
  #pragma unroll
  for (int m = 1; m < 64; m <<= 1) part += __shfl_xor(part, m, 64);
  if (lane == 0) {
    float p = 1.f / (1.f + __expf(-(part + weffc[2048])));
    out[g] = p;
  }
}

extern "C" void kernel_launch(void* const* d_in, const int* in_sizes, int n_in,
                              void* d_out, int out_size, void* d_ws, size_t ws_size,
                              hipStream_t stream) {
  const float* feat = (const float*)d_in[0];
  const int* edges = (const int*)d_in[1];
  const float* W1 = (const float*)d_in[2];
  const float* as1 = (const float*)d_in[3];
  const float* ad1 = (const float*)d_in[4];
  const float* b1 = (const float*)d_in[5];
  const float* W2 = (const float*)d_in[6];
  const float* as2 = (const float*)d_in[7];
  const float* ad2 = (const float*)d_in[8];
  const float* b2 = (const float*)d_in[9];
  const float* Wl = (const float*)d_in[10];
  const float* bl = (const float*)d_in[11];
  const float* Wp = (const float*)d_in[12];
  const float* bp = (const float*)d_in[13];

  unsigned short* wfrag = (unsigned short*)d_ws;          // 65536 B
  float* weffc = (float*)((char*)d_ws + 65536);           // 2049 f32

  gat_setup_kernel<<<17, 256, 0, stream>>>(W1, W2, Wl, bl, Wp, bp, wfrag, weffc);
  gat_kernel<<<8192, 256, 0, stream>>>(feat, edges, as1, ad1, b1, as2, ad2, b2,
                                       wfrag, weffc, (float*)d_out);
}